// Round 2
// baseline (510.873 us; speedup 1.0000x reference)
//
#include <hip/hip_runtime.h>

#define NN     256
#define NF     127
#define DIM    128
#define NH     8
#define DH     64
#define INNER  512
#define DEPTH  6
#define NB     512
#define R      4          // rows per block
#define ATTN_SCALE 0.125f
#define LN_EPS 1e-5f

#define FMA4(A_, S_, V_) { A_.x=fmaf(S_,(V_).x,A_.x); A_.y=fmaf(S_,(V_).y,A_.y); \
                           A_.z=fmaf(S_,(V_).z,A_.z); A_.w=fmaf(S_,(V_).w,A_.w); }

__device__ __forceinline__ float wred_sum(float v){
#pragma unroll
  for(int o=32;o;o>>=1) v += __shfl_xor(v,o);
  return v;
}

// 512 thr = 8 waves; row r = t>>7 spans waves 2r,2r+1. sred must have >= 8 floats.
// Returns per-row sum of v over that row's 128 threads.
__device__ __forceinline__ float row_sum128(float v, float* sred, int t){
  v = wred_sum(v);
  __syncthreads();
  if((t&63)==0) sred[t>>6] = v;
  __syncthreads();
  const int r2 = (t>>7)<<1;
  return sred[r2] + sred[r2+1];
}

// LayerNorm on R rows of DIM: in[t] -> out[t]  (t == r*128+d exactly)
__device__ __forceinline__ void dev_ln4(const float* in, float* out,
                                        const float* g, const float* b,
                                        float* sred, int t){
  const int d = t&127;
  float v = in[t];
  float m = row_sum128(v, sred, t) * (1.f/DIM);
  float dv = v - m;
  float var = row_sum128(dv*dv, sred, t) * (1.f/DIM);
  out[t] = dv * rsqrtf(var + LN_EPS) * g[d] + b[d];
  __syncthreads();
}

// gated residual: nd = o*sig(gs) + nd*(1-sig(gs)), gs per row
__device__ __forceinline__ void dev_gate(const float* o, float* nd, const float* Wg,
                                         float* sred, int t){
  const int d = t&127;
  float ov = o[t], rv = nd[t];
  float gv = ov*Wg[d] + rv*Wg[DIM+d] + (ov-rv)*Wg[2*DIM+d];
  float gate = 1.f/(1.f + expf(-row_sum128(gv, sred, t)));
  nd[t] = ov*gate + rv*(1.f-gate);
  __syncthreads();
}

// X[R][128] @ W[128][512]: partials -> SC[(fq*R+r)*512 + c]; each W elem loaded once.
__device__ __forceinline__ void mm128_512_part(const float* xin, const float* W,
                                               float* SC, int t){
  const int cg4 = (t&127)<<2, fq = t>>7;
  float4 a0=make_float4(0.f,0.f,0.f,0.f), a1=a0, a2=a0, a3=a0;
#pragma unroll 8
  for(int f=fq*32; f<fq*32+32; f++){
    float4 wv = *(const float4*)(W + f*INNER + cg4);
    float v0=xin[f], v1=xin[DIM+f], v2=xin[2*DIM+f], v3=xin[3*DIM+f];
    FMA4(a0,v0,wv); FMA4(a1,v1,wv); FMA4(a2,v2,wv); FMA4(a3,v3,wv);
  }
  float* p = SC + (fq*R)*INNER + cg4;
  *(float4*)(p)           = a0;
  *(float4*)(p +   INNER) = a1;
  *(float4*)(p + 2*INNER) = a2;
  *(float4*)(p + 3*INNER) = a3;
}

// X[R][128] @ W[128][1024]: partials -> SC[(fh*R+r)*1024 + c]
__device__ __forceinline__ void mm128_1024_part(const float* xin, const float* W,
                                                float* SC, int t){
  const int cg4 = (t&255)<<2, fh = t>>8;
  float4 a0=make_float4(0.f,0.f,0.f,0.f), a1=a0, a2=a0, a3=a0;
#pragma unroll 8
  for(int f=fh*64; f<fh*64+64; f++){
    float4 wv = *(const float4*)(W + f*(2*INNER) + cg4);
    float v0=xin[f], v1=xin[DIM+f], v2=xin[2*DIM+f], v3=xin[3*DIM+f];
    FMA4(a0,v0,wv); FMA4(a1,v1,wv); FMA4(a2,v2,wv); FMA4(a3,v3,wv);
  }
  float* p = SC + (fh*R)*(2*INNER) + cg4;
  *(float4*)(p)             = a0;
  *(float4*)(p +   2*INNER) = a1;
  *(float4*)(p + 2*2*INNER) = a2;
  *(float4*)(p + 3*2*INNER) = a3;
}

// A[R][512] @ W[512][128]: partials -> SC[(fg*R+r)*128 + c], fg in [0,16)
__device__ __forceinline__ void mm512_128_part(const float* ain, const float* W,
                                               float* SC, int t){
  const int cg4 = (t&31)<<2, fg = t>>5;
  float4 a0=make_float4(0.f,0.f,0.f,0.f), a1=a0, a2=a0, a3=a0;
#pragma unroll 8
  for(int f=fg*32; f<fg*32+32; f++){
    float4 wv = *(const float4*)(W + f*DIM + cg4);
    float v0=ain[f], v1=ain[INNER+f], v2=ain[2*INNER+f], v3=ain[3*INNER+f];
    FMA4(a0,v0,wv); FMA4(a1,v1,wv); FMA4(a2,v2,wv); FMA4(a3,v3,wv);
  }
  float* p = SC + (fg*R)*DIM + cg4;
  *(float4*)(p)         = a0;
  *(float4*)(p +   DIM) = a1;
  *(float4*)(p + 2*DIM) = a2;
  *(float4*)(p + 3*DIM) = a3;
}

// reduce 16 f-group partials -> o128[t] (+bias); conflict-free (d consecutive)
__device__ __forceinline__ void red512_128(const float* SC, const float* bias,
                                           float* o128, int t){
  const int r = t>>7, d = t&127;
  float s = bias[d];
#pragma unroll
  for(int fg=0; fg<16; fg++) s += SC[(fg*R + r)*DIM + d];
  o128[t] = s;
}

// full QKV for rows i0..i0+3 from xs (LDS). q row-major, k transposed [c][j], v row-major.
__device__ __forceinline__ void dev_qkv(const float* xs, int i0,
    const float* Wq, const float* bq, const float* Wkv, const float* bkv,
    const float* be, float* qg, float* kT, float* vg, float* SC, int t){
  mm128_512_part(xs, Wq, SC, t);
  __syncthreads();
#pragma unroll
  for(int cc=0; cc<4; cc++){
    int idx = cc*512 + t;
    int r = idx>>9, c = idx&511;
    float s = bq[c] + SC[r*INNER+c] + SC[(R+r)*INNER+c]
                    + SC[(2*R+r)*INNER+c] + SC[(3*R+r)*INNER+c];
    qg[(i0+r)*INNER + c] = s;
  }
  __syncthreads();
  mm128_1024_part(xs, Wkv, SC, t);
  __syncthreads();
#pragma unroll
  for(int cc=0; cc<8; cc++){
    int idx = cc*512 + t;
    int r = idx>>10, c = idx&1023;
    float s = bkv[c] + SC[r*(2*INNER)+c] + SC[(R+r)*(2*INNER)+c];
    if(c < INNER) kT[c*NN + i0 + r]            = s + be[c];
    else          vg[(i0+r)*INNER + (c-INNER)] = s + be[c-INNER];
  }
  __syncthreads();
}

// ---- layer 0: node-init + LN1 + QKV, 4 rows/block ----
__global__ __launch_bounds__(512) void k_qkv0(const float* atom_emb, const float* noise,
    float* nodes, const float* ln1_g, const float* ln1_b,
    const float* Wq, const float* bq, const float* Wkv, const float* bkv, const float* be,
    float* qg, float* kT, float* vg){
  __shared__ __align__(16) float SC[8192];
  __shared__ float nd[R*DIM], xsm[R*DIM], sred[8];
  const int t = threadIdx.x, i0 = blockIdx.x*R;
  {
    const int r = t>>7, d = t&127;
    float v = (d<NF)? atom_emb[(i0+r)*NF + d] : noise[0];
    nd[t] = v;
    nodes[i0*DIM + t] = v;
  }
  __syncthreads();
  dev_ln4(nd, xsm, ln1_g, ln1_b, sred, t);
  dev_qkv(xsm, i0, Wq, bq, Wkv, bkv, be, qg, kT, vg, SC, t);
}

// ---- fused layer, 4 rows/block (grid 64 x 512) ----
__global__ __launch_bounds__(512) void k_layer(
    float* nodes, const float* qg, const float* kT, const float* vg,
    float* qg_n, float* kT_n, float* vg_n,
    const int* bonds, const float* coords,
    const float* We,
    const float* Wo, const float* bo, const float* Wg1,
    const float* ln2_g, const float* ln2_b,
    const float* W1, const float* b1, const float* W2, const float* b2,
    const float* Wg2,
    const float* ln1_g_n, const float* ln1_b_n,
    const float* Wq_n, const float* bq_n, const float* Wkv_n, const float* bkv_n,
    const float* be_n,
    const float* out_w, const float* out_b, float* eout, int has_next)
{
  __shared__ __align__(16) float SC[8192];      // aW[r][h][256] in attn; matmul partials after
  __shared__ __align__(16) float qs[R*INNER];   // q; later FFN hidden
  __shared__ __align__(16) float eb[3*R*NN];    // edge x/y/z; o128+sred alias (dead after attn)
  __shared__ __align__(16) float ao[R*INNER];   // attention output
  __shared__ float nd[R*DIM], xsm[R*DIM];
  float* o128 = eb;            // [R*DIM]
  float* sred = eb + R*DIM;    // [8]
  const int t = threadIdx.x, i0 = blockIdx.x*R;

  // ---- load state, zero edge rows ----
  nd[t] = nodes[i0*DIM + t];
#pragma unroll
  for(int cc=0; cc<4; cc++) qs[cc*512 + t] = qg[i0*INNER + cc*512 + t];
#pragma unroll
  for(int cc=0; cc<6; cc++) eb[cc*512 + t] = 0.f;
  __syncthreads();

  // ---- scatter bonds touching rows i0..i0+3 (duplicates write identical values) ----
  {
    const int bi = bonds[2*t], bj = bonds[2*t+1];
    const bool hi = (bi>=i0 && bi<i0+R), hj = (bj>=i0 && bj<i0+R);
    if(hi || hj){
      float dx = coords[3*bi+0] - coords[3*bj+0];
      float dy = coords[3*bi+1] - coords[3*bj+1];
      float dz = coords[3*bi+2] - coords[3*bj+2];
      if(hi){ int r = bi-i0;
        eb[r*NN+bj]=dx;  eb[(R+r)*NN+bj]=dy;  eb[(2*R+r)*NN+bj]=dz;  }
      if(hj){ int r = bj-i0;
        eb[r*NN+bi]=-dx; eb[(R+r)*NN+bi]=-dy; eb[(2*R+r)*NN+bi]=-dz; }
    }
  }
  __syncthreads();

  // ---- attention: wave = head, 4 rows per wave ----
  {
    const int h = t>>6, l = t&63, j0 = l<<2;
    const int qb = h*DH;
    // qwe[r][c] = q_r[h-slice] . We[c, h-slice]  (wave-reduced, kept in registers)
    float qwe[R][3];
    {
      float qv0=qs[0*INNER+qb+l], qv1=qs[1*INNER+qb+l],
            qv2=qs[2*INNER+qb+l], qv3=qs[3*INNER+qb+l];
#pragma unroll
      for(int c=0;c<3;c++){
        float wv = We[c*INNER + qb + l];
        qwe[0][c]=qv0*wv; qwe[1][c]=qv1*wv; qwe[2][c]=qv2*wv; qwe[3][c]=qv3*wv;
      }
#pragma unroll
      for(int o=32;o;o>>=1)
#pragma unroll
        for(int r=0;r<R;r++){
          qwe[r][0]+=__shfl_xor(qwe[r][0],o);
          qwe[r][1]+=__shfl_xor(qwe[r][1],o);
          qwe[r][2]+=__shfl_xor(qwe[r][2],o);
        }
    }
    // QK^T: lane l scores j0..j0+3 for all 4 rows (each kT elem loaded once/block)
    const float* kTh = kT + qb*NN;
    float s[R][4];
#pragma unroll
    for(int r=0;r<R;r++){ s[r][0]=0.f; s[r][1]=0.f; s[r][2]=0.f; s[r][3]=0.f; }
#pragma unroll 8
    for(int o=0;o<DH;o++){
      float4 kk = *(const float4*)(kTh + o*NN + j0);
#pragma unroll
      for(int r=0;r<R;r++){
        float qv = qs[r*INNER + qb + o];
        s[r][0]=fmaf(qv,kk.x,s[r][0]); s[r][1]=fmaf(qv,kk.y,s[r][1]);
        s[r][2]=fmaf(qv,kk.z,s[r][2]); s[r][3]=fmaf(qv,kk.w,s[r][3]);
      }
    }
#pragma unroll
    for(int r=0;r<R;r++){
      float4 ex = *(const float4*)(eb + r*NN + j0);
      float4 ey = *(const float4*)(eb + (R+r)*NN + j0);
      float4 ez = *(const float4*)(eb + (2*R+r)*NN + j0);
      float w0=qwe[r][0], w1=qwe[r][1], w2=qwe[r][2];
      s[r][0] = (s[r][0] + w0*ex.x + w1*ey.x + w2*ez.x)*ATTN_SCALE;
      s[r][1] = (s[r][1] + w0*ex.y + w1*ey.y + w2*ez.y)*ATTN_SCALE;
      s[r][2] = (s[r][2] + w0*ex.z + w1*ey.z + w2*ez.z)*ATTN_SCALE;
      s[r][3] = (s[r][3] + w0*ex.w + w1*ey.w + w2*ez.w)*ATTN_SCALE;
    }
    // softmax per row (batched butterflies for ILP)
    float mx[R];
#pragma unroll
    for(int r=0;r<R;r++) mx[r]=fmaxf(fmaxf(s[r][0],s[r][1]),fmaxf(s[r][2],s[r][3]));
#pragma unroll
    for(int o=32;o;o>>=1)
#pragma unroll
      for(int r=0;r<R;r++) mx[r]=fmaxf(mx[r],__shfl_xor(mx[r],o));
    float sm[R];
#pragma unroll
    for(int r=0;r<R;r++){
      s[r][0]=expf(s[r][0]-mx[r]); s[r][1]=expf(s[r][1]-mx[r]);
      s[r][2]=expf(s[r][2]-mx[r]); s[r][3]=expf(s[r][3]-mx[r]);
      sm[r]=s[r][0]+s[r][1]+s[r][2]+s[r][3];
    }
#pragma unroll
    for(int o=32;o;o>>=1)
#pragma unroll
      for(int r=0;r<R;r++) sm[r]+=__shfl_xor(sm[r],o);
    // attn weights -> SC(aW); edge c-terms
    float cE[R][3];
#pragma unroll
    for(int r=0;r<R;r++){
      float inv = 1.f/sm[r];
      float a0=s[r][0]*inv, a1=s[r][1]*inv, a2=s[r][2]*inv, a3=s[r][3]*inv;
      *(float4*)(SC + ((r<<3)+h)*NN + j0) = make_float4(a0,a1,a2,a3);
      float4 ex = *(const float4*)(eb + r*NN + j0);
      float4 ey = *(const float4*)(eb + (R+r)*NN + j0);
      float4 ez = *(const float4*)(eb + (2*R+r)*NN + j0);
      cE[r][0]=a0*ex.x+a1*ex.y+a2*ex.z+a3*ex.w;
      cE[r][1]=a0*ey.x+a1*ey.y+a2*ey.z+a3*ey.w;
      cE[r][2]=a0*ez.x+a1*ez.y+a2*ez.z+a3*ez.w;
    }
#pragma unroll
    for(int o=32;o;o>>=1)
#pragma unroll
      for(int r=0;r<R;r++){
        cE[r][0]+=__shfl_xor(cE[r][0],o);
        cE[r][1]+=__shfl_xor(cE[r][1],o);
        cE[r][2]+=__shfl_xor(cE[r][2],o);
      }
    __builtin_amdgcn_wave_barrier();  // order aW writes before same-wave aW reads
    // PV: lane l -> dims dq..dq+3, j-range jg*64..+63 (rotated start: bank-spread aW reads)
    const int dq=(l&15)<<2, jg=l>>4;
    const float* vb = vg + qb + dq;
    float4 acc0=make_float4(0.f,0.f,0.f,0.f), acc1=acc0, acc2=acc0, acc3=acc0;
#pragma unroll 8
    for(int jj=0;jj<64;jj++){
      int j = (jg<<6) + ((jj + (jg<<3)) & 63);
      float4 vv = *(const float4*)(vb + j*INNER);
      float w0 = SC[(0*NH+h)*NN + j];
      float w1 = SC[(1*NH+h)*NN + j];
      float w2 = SC[(2*NH+h)*NN + j];
      float w3 = SC[(3*NH+h)*NN + j];
      FMA4(acc0,w0,vv); FMA4(acc1,w1,vv); FMA4(acc2,w2,vv); FMA4(acc3,w3,vv);
    }
#pragma unroll
    for(int o=16;o<64;o<<=1){
      acc0.x+=__shfl_xor(acc0.x,o); acc0.y+=__shfl_xor(acc0.y,o);
      acc0.z+=__shfl_xor(acc0.z,o); acc0.w+=__shfl_xor(acc0.w,o);
      acc1.x+=__shfl_xor(acc1.x,o); acc1.y+=__shfl_xor(acc1.y,o);
      acc1.z+=__shfl_xor(acc1.z,o); acc1.w+=__shfl_xor(acc1.w,o);
      acc2.x+=__shfl_xor(acc2.x,o); acc2.y+=__shfl_xor(acc2.y,o);
      acc2.z+=__shfl_xor(acc2.z,o); acc2.w+=__shfl_xor(acc2.w,o);
      acc3.x+=__shfl_xor(acc3.x,o); acc3.y+=__shfl_xor(acc3.y,o);
      acc3.z+=__shfl_xor(acc3.z,o); acc3.w+=__shfl_xor(acc3.w,o);
    }
    if(l<16){
      float4 we0 = *(const float4*)(We + 0*INNER + qb + dq);
      float4 we1 = *(const float4*)(We + 1*INNER + qb + dq);
      float4 we2 = *(const float4*)(We + 2*INNER + qb + dq);
      float4 ov;
      ov.x=acc0.x+cE[0][0]*we0.x+cE[0][1]*we1.x+cE[0][2]*we2.x;
      ov.y=acc0.y+cE[0][0]*we0.y+cE[0][1]*we1.y+cE[0][2]*we2.y;
      ov.z=acc0.z+cE[0][0]*we0.z+cE[0][1]*we1.z+cE[0][2]*we2.z;
      ov.w=acc0.w+cE[0][0]*we0.w+cE[0][1]*we1.w+cE[0][2]*we2.w;
      *(float4*)(ao + 0*INNER + qb + dq) = ov;
      ov.x=acc1.x+cE[1][0]*we0.x+cE[1][1]*we1.x+cE[1][2]*we2.x;
      ov.y=acc1.y+cE[1][0]*we0.y+cE[1][1]*we1.y+cE[1][2]*we2.y;
      ov.z=acc1.z+cE[1][0]*we0.z+cE[1][1]*we1.z+cE[1][2]*we2.z;
      ov.w=acc1.w+cE[1][0]*we0.w+cE[1][1]*we1.w+cE[1][2]*we2.w;
      *(float4*)(ao + 1*INNER + qb + dq) = ov;
      ov.x=acc2.x+cE[2][0]*we0.x+cE[2][1]*we1.x+cE[2][2]*we2.x;
      ov.y=acc2.y+cE[2][0]*we0.y+cE[2][1]*we1.y+cE[2][2]*we2.y;
      ov.z=acc2.z+cE[2][0]*we0.z+cE[2][1]*we1.z+cE[2][2]*we2.z;
      ov.w=acc2.w+cE[2][0]*we0.w+cE[2][1]*we1.w+cE[2][2]*we2.w;
      *(float4*)(ao + 2*INNER + qb + dq) = ov;
      ov.x=acc3.x+cE[3][0]*we0.x+cE[3][1]*we1.x+cE[3][2]*we2.x;
      ov.y=acc3.y+cE[3][0]*we0.y+cE[3][1]*we1.y+cE[3][2]*we2.y;
      ov.z=acc3.z+cE[3][0]*we0.z+cE[3][1]*we1.z+cE[3][2]*we2.z;
      ov.w=acc3.w+cE[3][0]*we0.w+cE[3][1]*we1.w+cE[3][2]*we2.w;
      *(float4*)(ao + 3*INNER + qb + dq) = ov;
    }
  }
  __syncthreads();    // edges (eb) dead from here; o128/sred alias becomes live

  // ---- Wo + gate1 ----
  mm512_128_part(ao, Wo, SC, t);
  __syncthreads();
  red512_128(SC, bo, o128, t);
  __syncthreads();
  dev_gate(o128, nd, Wg1, sred, t);

  // ---- LN2 + FFN(gelu exact) + gate2 ----
  dev_ln4(nd, xsm, ln2_g, ln2_b, sred, t);
  mm128_512_part(xsm, W1, SC, t);
  __syncthreads();
#pragma unroll
  for(int cc=0; cc<4; cc++){
    int idx = cc*512 + t;
    int r = idx>>9, c = idx&511;
    float a = b1[c] + SC[r*INNER+c] + SC[(R+r)*INNER+c]
                    + SC[(2*R+r)*INNER+c] + SC[(3*R+r)*INNER+c];
    qs[idx] = 0.5f*a*(1.f + erff(a*0.70710678118654752440f));
  }
  __syncthreads();
  mm512_128_part(qs, W2, SC, t);
  __syncthreads();
  red512_128(SC, b2, o128, t);
  __syncthreads();
  dev_gate(o128, nd, Wg2, sred, t);

  nodes[i0*DIM + t] = nd[t];

  if(has_next){
    // next layer's LN1+QKV into the other buffer set
    dev_ln4(nd, xsm, ln1_g_n, ln1_b_n, sred, t);
    dev_qkv(xsm, i0, Wq_n, bq_n, Wkv_n, bkv_n, be_n, qg_n, kT_n, vg_n, SC, t);
  } else {
    // fused energy head: out[i] = nodes[i] . out_w + out_b
    float ev = nd[t] * out_w[t&127];
    float es = row_sum128(ev, sred, t);
    if((t&127)==0) eout[i0 + (t>>7)] = es + out_b[0];
  }
}

extern "C" void kernel_launch(void* const* d_in, const int* in_sizes, int n_in,
                              void* d_out, int out_size, void* d_ws, size_t ws_size,
                              hipStream_t stream){
  const float* coords   = (const float*)d_in[0];
  const int*   bonds    = (const int*  )d_in[1];
  const float* noise    = (const float*)d_in[2];
  const float* atom_emb = (const float*)d_in[3];
  const float* ln1_g = (const float*)d_in[4];
  const float* ln1_b = (const float*)d_in[5];
  const float* Wq    = (const float*)d_in[6];
  const float* bq    = (const float*)d_in[7];
  const float* Wkv   = (const float*)d_in[8];
  const float* bkv   = (const float*)d_in[9];
  const float* We    = (const float*)d_in[10];
  const float* be    = (const float*)d_in[11];
  const float* Wo    = (const float*)d_in[12];
  const float* bo    = (const float*)d_in[13];
  const float* Wg1   = (const float*)d_in[14];
  const float* ln2_g = (const float*)d_in[15];
  const float* ln2_b = (const float*)d_in[16];
  const float* W1    = (const float*)d_in[17];
  const float* b1    = (const float*)d_in[18];
  const float* W2    = (const float*)d_in[19];
  const float* b2    = (const float*)d_in[20];
  const float* Wg2   = (const float*)d_in[21];
  const float* out_w = (const float*)d_in[22];
  const float* out_b = (const float*)d_in[23];

  // workspace (fp32): same layout as before, ~3.3 MB
  float* ws = (float*)d_ws;
  float* nodes   = ws;                              // 32768 floats
  float* qbuf[2] = { ws +  32768, ws + 163840 };    // 131072 each
  float* kbuf[2] = { ws + 294912, ws + 425984 };    // transposed [c][j]
  float* vbuf[2] = { ws + 557056, ws + 688128 };    // row-major [j][c]

  k_qkv0<<<NN/R, 512, 0, stream>>>(atom_emb, noise, nodes, ln1_g, ln1_b,
                                   Wq, bq, Wkv, bkv, be,
                                   qbuf[0], kbuf[0], vbuf[0]);
  for(int l=0; l<DEPTH; l++){
    int cur = l&1, nxt = cur^1;
    int has_next = (l < DEPTH-1);
    int ln = has_next ? l+1 : l;    // keep pointers valid when unused
    k_layer<<<NN/R, 512, 0, stream>>>(
      nodes, qbuf[cur], kbuf[cur], vbuf[cur],
      qbuf[nxt], kbuf[nxt], vbuf[nxt],
      bonds, coords,
      We  + (size_t)l*3*INNER,
      Wo  + (size_t)l*INNER*DIM, bo + (size_t)l*DIM, Wg1 + (size_t)l*3*DIM,
      ln2_g + (size_t)l*DIM, ln2_b + (size_t)l*DIM,
      W1  + (size_t)l*DIM*4*DIM, b1 + (size_t)l*4*DIM,
      W2  + (size_t)l*4*DIM*DIM, b2 + (size_t)l*DIM, Wg2 + (size_t)l*3*DIM,
      ln1_g + (size_t)ln*DIM, ln1_b + (size_t)ln*DIM,
      Wq  + (size_t)ln*DIM*INNER, bq + (size_t)ln*INNER,
      Wkv + (size_t)ln*DIM*2*INNER, bkv + (size_t)ln*2*INNER,
      be  + (size_t)ln*INNER,
      out_w, out_b, (float*)d_out, has_next);
  }
}

// Round 3
// 304.876 us; speedup vs baseline: 1.6757x; 1.6757x over previous
//
#include <hip/hip_runtime.h>

#define NN     256
#define NF     127
#define DIM    128
#define NH     8
#define DH     64
#define INNER  512
#define DEPTH  6
#define NB     512
#define ATTN_SCALE 0.125f
#define LN_EPS 1e-5f

#define FMA4(A_, S_, V_) { A_.x=fmaf(S_,(V_).x,A_.x); A_.y=fmaf(S_,(V_).y,A_.y); \
                           A_.z=fmaf(S_,(V_).z,A_.z); A_.w=fmaf(S_,(V_).w,A_.w); }

__device__ __forceinline__ float wred_sum(float v){
#pragma unroll
  for(int o=32;o;o>>=1) v += __shfl_xor(v,o);
  return v;
}
__device__ __forceinline__ float wred_max(float v){
#pragma unroll
  for(int o=32;o;o>>=1) v = fmaxf(v,__shfl_xor(v,o));
  return v;
}
__device__ __forceinline__ float2 wred_sum2(float a, float b){
#pragma unroll
  for(int o=32;o;o>>=1){ a += __shfl_xor(a,o); b += __shfl_xor(b,o); }
  return make_float2(a,b);
}

// In-wave LayerNorm of a 128-dim row held as (n0,n1) = dims (l, l+64) per lane.
// Single pass: sum and sumsq in one butterfly. No barriers.
__device__ __forceinline__ void ln_wave(float n0, float n1,
                                        const float* g, const float* b, int l,
                                        float& x0, float& x1){
  float2 sv = wred_sum2(n0+n1, n0*n0+n1*n1);
  float m  = sv.x*(1.f/DIM);
  float var = sv.y*(1.f/DIM) - m*m;
  float rs = rsqrtf(var + LN_EPS);
  x0 = (n0-m)*rs*g[l]    + b[l];
  x1 = (n1-m)*rs*g[64+l] + b[64+l];
}

// In-wave gated residual: nd = o*sig(gs)+nd*(1-sig(gs)); gs = row sum. No barriers.
__device__ __forceinline__ void gate_wave(float o0, float o1, float& n0, float& n1,
                                          const float* Wg, int l){
  float gv = o0*Wg[l]    + n0*Wg[DIM+l]    + (o0-n0)*Wg[2*DIM+l]
           + o1*Wg[64+l] + n1*Wg[DIM+64+l] + (o1-n1)*Wg[2*DIM+64+l];
  gv = wred_sum(gv);
  float gate = 1.f/(1.f + expf(-gv));
  n0 = o0*gate + n0*(1.f-gate);
  n1 = o1*gate + n1*(1.f-gate);
}

// x[128] (LDS) @ W[128][512] -> partials SC[fq*512+c], fq in [0,4)
__device__ __forceinline__ void mvp128_512(const float* xin, const float* W,
                                           float* SC, int t){
  const int cg4 = (t&127)<<2, fq = t>>7;
  float4 acc = make_float4(0.f,0.f,0.f,0.f);
#pragma unroll 8
  for(int f=fq*32; f<fq*32+32; f++){
    float4 wv = *(const float4*)(W + f*INNER + cg4);
    float xv = xin[f];
    FMA4(acc, xv, wv);
  }
  *(float4*)(SC + fq*INNER + cg4) = acc;
}

// x[128] (LDS) @ W[128][1024] -> partials SC[rh*1024+c], rh in [0,2)
__device__ __forceinline__ void mvp128_1024(const float* xin, const float* W,
                                            float* SC, int t){
  const int cg4 = (t&255)<<2, rh = t>>8;
  float4 acc = make_float4(0.f,0.f,0.f,0.f);
#pragma unroll 8
  for(int f=rh*64; f<rh*64+64; f++){
    float4 wv = *(const float4*)(W + f*(2*INNER) + cg4);
    float xv = xin[f];
    FMA4(acc, xv, wv);
  }
  *(float4*)(SC + rh*(2*INNER) + cg4) = acc;
}

// a[512] (LDS) @ W[512][128] -> partials SC[fg*128+c], fg in [0,16)
__device__ __forceinline__ void mvp512_128(const float* ain, const float* W,
                                           float* SC, int t){
  const int cg4 = (t&31)<<2, fg = t>>5;
  float4 acc = make_float4(0.f,0.f,0.f,0.f);
#pragma unroll 8
  for(int f=fg*32; f<fg*32+32; f++){
    float4 wv = *(const float4*)(W + f*DIM + cg4);
    float av = ain[f];
    FMA4(acc, av, wv);
  }
  *(float4*)(SC + fg*DIM + cg4) = acc;
}

// LN1 output xs[128] (LDS) -> next-layer q/k/v.  4 barriers inside.
__device__ __forceinline__ void qkv_tail(const float* xs, int i,
    const float* Wq, const float* bq, const float* Wkv, const float* bkv,
    const float* be, float* qgn, float* kTn, float* vgn, float* SC, int t){
  mvp128_512(xs, Wq, SC, t);
  __syncthreads();
  qgn[i*INNER + t] = bq[t] + SC[t] + SC[INNER+t] + SC[2*INNER+t] + SC[3*INNER+t];
  __syncthreads();                 // SC reuse
  mvp128_1024(xs, Wkv, SC, t);
  __syncthreads();
#pragma unroll
  for(int cc=0; cc<2; cc++){
    int c = t + cc*512;
    float s = bkv[c] + SC[c] + SC[2*INNER+c];
    if(c < INNER) kTn[c*NN + i]            = s + be[c];
    else          vgn[i*INNER + c - INNER] = s + be[c-INNER];
  }
}

// ---- layer 0: node-init + LN1 (in-wave) + QKV ----
__global__ __launch_bounds__(512) void k_qkv0(const float* atom_emb, const float* noise,
    float* nodes, const float* ln1_g, const float* ln1_b,
    const float* Wq, const float* bq, const float* Wkv, const float* bkv, const float* be,
    float* qg, float* kT, float* vg){
  __shared__ __align__(16) float SC[2048];
  __shared__ __align__(16) float xsm[DIM];
  const int t = threadIdx.x, i = blockIdx.x;
  const int w = t>>6, l = t&63;
  // every wave redundantly builds the row (128 floats) in registers
  float nd0 = (l<NF)?      atom_emb[i*NF + l]      : noise[0];
  float nd1 = (64+l<NF)?   atom_emb[i*NF + 64 + l] : noise[0];
  if(w==0){ nodes[i*DIM + l] = nd0; nodes[i*DIM + 64 + l] = nd1; }
  float x0, x1;
  ln_wave(nd0, nd1, ln1_g, ln1_b, l, x0, x1);
  xsm[l] = x0; xsm[64+l] = x1;     // all waves write identical values (benign)
  __syncthreads();
  qkv_tail(xsm, i, Wq, bq, Wkv, bkv, be, qg, kT, vg, SC, t);
}

// ---- fused per-row layer: 12 block barriers total ----
__global__ __launch_bounds__(512) void k_layer(
    float* nodes, const float* qg, const float* kT, const float* vg,
    float* qg_n, float* kT_n, float* vg_n,
    const int* bonds, const float* coords,
    const float* We,
    const float* Wo, const float* bo, const float* Wg1,
    const float* ln2_g, const float* ln2_b,
    const float* W1, const float* b1, const float* W2, const float* b2,
    const float* Wg2,
    const float* ln1_g_n, const float* ln1_b_n,
    const float* Wq_n, const float* bq_n, const float* Wkv_n, const float* bkv_n,
    const float* be_n,
    const float* out_w, const float* out_b, float* eout, int has_next)
{
  __shared__ __align__(16) float SC[2048];   // matmul partials; aW[h][256] during attn
  __shared__ __align__(16) float qs[INNER];  // q row; later FFN hidden
  __shared__ __align__(16) float ao[INNER];  // attention output row
  __shared__ __align__(16) float eb[3*NN];   // edge planes [c][j]
  __shared__ __align__(16) float xsm[DIM];
  const int t = threadIdx.x, i = blockIdx.x;
  const int w = t>>6, l = t&63;

  // ---- init: q row -> LDS, edge planes zero, node row -> regs (per-wave redundant)
  qs[t] = qg[i*INNER + t];
  eb[t&511] = 0.f;                 // t in [0,512): covers 0..511
  if(t < 256) eb[512 + t] = 0.f;
  float nd0 = nodes[i*DIM + l];
  float nd1 = nodes[i*DIM + 64 + l];
  __syncthreads();                               // B1

  // ---- scatter bonds touching row i (duplicate writes carry identical values)
  {
    const int bi = bonds[2*t], bj = bonds[2*t+1];
    if(bi==i || bj==i){
      float dx = coords[3*bi+0] - coords[3*bj+0];
      float dy = coords[3*bi+1] - coords[3*bj+1];
      float dz = coords[3*bi+2] - coords[3*bj+2];
      if(bi==i){ eb[bj]=dx;  eb[NN+bj]=dy;  eb[2*NN+bj]=dz;  }
      if(bj==i){ eb[bi]=-dx; eb[NN+bi]=-dy; eb[2*NN+bi]=-dz; }
    }
  }
  __syncthreads();                               // B2

  // ---- attention: wave w == head w; zero block barriers inside ----
  {
    const int h = w, j0 = l<<2, qb = h*DH;
    // qwe_c = q[h-slice] . We[c, h-slice]  (in-wave butterfly)
    float qwe0, qwe1, qwe2;
    {
      float qv = qs[qb + l];
      qwe0 = qv*We[0*INNER + qb + l];
      qwe1 = qv*We[1*INNER + qb + l];
      qwe2 = qv*We[2*INNER + qb + l];
#pragma unroll
      for(int o=32;o;o>>=1){
        qwe0 += __shfl_xor(qwe0,o); qwe1 += __shfl_xor(qwe1,o); qwe2 += __shfl_xor(qwe2,o);
      }
    }
    // QK^T: lane l -> scores j0..j0+3
    const float* kTh = kT + qb*NN;
    float s0=0.f,s1=0.f,s2=0.f,s3=0.f;
#pragma unroll 8
    for(int o=0;o<DH;o++){
      float qv = qs[qb + o];
      float4 kk = *(const float4*)(kTh + o*NN + j0);
      s0=fmaf(qv,kk.x,s0); s1=fmaf(qv,kk.y,s1); s2=fmaf(qv,kk.z,s2); s3=fmaf(qv,kk.w,s3);
    }
    float4 ex = *(const float4*)(eb + j0);
    float4 ey = *(const float4*)(eb + NN + j0);
    float4 ez = *(const float4*)(eb + 2*NN + j0);
    s0 = (s0 + qwe0*ex.x + qwe1*ey.x + qwe2*ez.x)*ATTN_SCALE;
    s1 = (s1 + qwe0*ex.y + qwe1*ey.y + qwe2*ez.y)*ATTN_SCALE;
    s2 = (s2 + qwe0*ex.z + qwe1*ey.z + qwe2*ez.z)*ATTN_SCALE;
    s3 = (s3 + qwe0*ex.w + qwe1*ey.w + qwe2*ez.w)*ATTN_SCALE;
    float mx = wred_max(fmaxf(fmaxf(s0,s1),fmaxf(s2,s3)));
    float p0=expf(s0-mx), p1=expf(s1-mx), p2=expf(s2-mx), p3=expf(s3-mx);
    float inv = 1.f / wred_sum(p0+p1+p2+p3);
    float a0=p0*inv, a1=p1*inv, a2=p2*inv, a3=p3*inv;
    *(float4*)(SC + h*NN + j0) = make_float4(a0,a1,a2,a3);
    // edge moment: c_c = sum_j a_j * eb[c][j]
    float c0 = a0*ex.x + a1*ex.y + a2*ex.z + a3*ex.w;
    float c1 = a0*ey.x + a1*ey.y + a2*ey.z + a3*ey.w;
    float c2 = a0*ez.x + a1*ez.y + a2*ez.z + a3*ez.w;
    c0 = wred_sum(c0); c1 = wred_sum(c1); c2 = wred_sum(c2);
    __builtin_amdgcn_wave_barrier();   // order aW writes before same-wave aW reads
    // PV: lane l -> dims dq..dq+3, j-range jg*64..+63 (rotated start: spread aW banks)
    const int dq = (l&15)<<2, jg = l>>4;
    const float* vb = vg + qb + dq;
    float4 acc = make_float4(0.f,0.f,0.f,0.f);
#pragma unroll 8
    for(int jj=0;jj<64;jj++){
      int j = (jg<<6) + ((jj + (jg<<3)) & 63);
      float a = SC[h*NN + j];
      float4 vv = *(const float4*)(vb + j*INNER);
      FMA4(acc, a, vv);
    }
#pragma unroll
    for(int o=16;o<64;o<<=1){
      acc.x += __shfl_xor(acc.x,o); acc.y += __shfl_xor(acc.y,o);
      acc.z += __shfl_xor(acc.z,o); acc.w += __shfl_xor(acc.w,o);
    }
    if(l<16){
      float4 we0 = *(const float4*)(We + 0*INNER + qb + dq);
      float4 we1 = *(const float4*)(We + 1*INNER + qb + dq);
      float4 we2 = *(const float4*)(We + 2*INNER + qb + dq);
      float4 ov;
      ov.x = acc.x + c0*we0.x + c1*we1.x + c2*we2.x;
      ov.y = acc.y + c0*we0.y + c1*we1.y + c2*we2.y;
      ov.z = acc.z + c0*we0.z + c1*we1.z + c2*we2.z;
      ov.w = acc.w + c0*we0.w + c1*we1.w + c2*we2.w;
      *(float4*)(ao + qb + dq) = ov;
    }
  }
  __syncthreads();                               // B3 (ao ready; SC free)

  // ---- Wo partial ----
  mvp512_128(ao, Wo, SC, t);
  __syncthreads();                               // B4
  // ---- per-wave: combine + gate1 + LN2 -> xsm (zero barriers) ----
  {
    float o0 = bo[l], o1 = bo[64+l];
#pragma unroll
    for(int fg=0; fg<16; fg++){ o0 += SC[fg*DIM + l]; o1 += SC[fg*DIM + 64 + l]; }
    gate_wave(o0, o1, nd0, nd1, Wg1, l);
    float x0, x1;
    ln_wave(nd0, nd1, ln2_g, ln2_b, l, x0, x1);
    xsm[l] = x0; xsm[64+l] = x1;
  }
  __syncthreads();                               // B5 (xsm ready; SC free)

  // ---- FFN ----
  mvp128_512(xsm, W1, SC, t);
  __syncthreads();                               // B6
  {
    float a = b1[t] + SC[t] + SC[INNER+t] + SC[2*INNER+t] + SC[3*INNER+t];
    qs[t] = 0.5f*a*(1.f + erff(a*0.70710678118654752440f));
  }
  __syncthreads();                               // B7 (hidden ready; SC free)
  mvp512_128(qs, W2, SC, t);
  __syncthreads();                               // B8
  // ---- per-wave: combine + gate2 + (LN1_next | energy) ----
  {
    float y0 = b2[l], y1 = b2[64+l];
#pragma unroll
    for(int fg=0; fg<16; fg++){ y0 += SC[fg*DIM + l]; y1 += SC[fg*DIM + 64 + l]; }
    gate_wave(y0, y1, nd0, nd1, Wg2, l);
    if(w==0){ nodes[i*DIM + l] = nd0; nodes[i*DIM + 64 + l] = nd1; }
    if(has_next){
      float x0, x1;
      ln_wave(nd0, nd1, ln1_g_n, ln1_b_n, l, x0, x1);
      xsm[l] = x0; xsm[64+l] = x1;
    } else if(w==0){
      float ev = nd0*out_w[l] + nd1*out_w[64+l];
      ev = wred_sum(ev);
      if(l==0) eout[i] = ev + out_b[0];
    }
  }
  if(has_next){
    __syncthreads();                             // B9 (xsm ready; SC free)
    qkv_tail(xsm, i, Wq_n, bq_n, Wkv_n, bkv_n, be_n, qg_n, kT_n, vg_n, SC, t); // B10-B12
  }
}

extern "C" void kernel_launch(void* const* d_in, const int* in_sizes, int n_in,
                              void* d_out, int out_size, void* d_ws, size_t ws_size,
                              hipStream_t stream){
  const float* coords   = (const float*)d_in[0];
  const int*   bonds    = (const int*  )d_in[1];
  const float* noise    = (const float*)d_in[2];
  const float* atom_emb = (const float*)d_in[3];
  const float* ln1_g = (const float*)d_in[4];
  const float* ln1_b = (const float*)d_in[5];
  const float* Wq    = (const float*)d_in[6];
  const float* bq    = (const float*)d_in[7];
  const float* Wkv   = (const float*)d_in[8];
  const float* bkv   = (const float*)d_in[9];
  const float* We    = (const float*)d_in[10];
  const float* be    = (const float*)d_in[11];
  const float* Wo    = (const float*)d_in[12];
  const float* bo    = (const float*)d_in[13];
  const float* Wg1   = (const float*)d_in[14];
  const float* ln2_g = (const float*)d_in[15];
  const float* ln2_b = (const float*)d_in[16];
  const float* W1    = (const float*)d_in[17];
  const float* b1    = (const float*)d_in[18];
  const float* W2    = (const float*)d_in[19];
  const float* b2    = (const float*)d_in[20];
  const float* Wg2   = (const float*)d_in[21];
  const float* out_w = (const float*)d_in[22];
  const float* out_b = (const float*)d_in[23];

  // workspace (fp32): ~3.3 MB
  float* ws = (float*)d_ws;
  float* nodes   = ws;                              // 32768 floats
  float* qbuf[2] = { ws +  32768, ws + 163840 };    // 131072 each
  float* kbuf[2] = { ws + 294912, ws + 425984 };    // transposed [c][j]
  float* vbuf[2] = { ws + 557056, ws + 688128 };    // row-major [j][c]

  k_qkv0<<<NN, 512, 0, stream>>>(atom_emb, noise, nodes, ln1_g, ln1_b,
                                 Wq, bq, Wkv, bkv, be,
                                 qbuf[0], kbuf[0], vbuf[0]);
  for(int l=0; l<DEPTH; l++){
    int cur = l&1, nxt = cur^1;
    int has_next = (l < DEPTH-1);
    int ln = has_next ? l+1 : l;    // keep pointers valid when unused
    k_layer<<<NN, 512, 0, stream>>>(
      nodes, qbuf[cur], kbuf[cur], vbuf[cur],
      qbuf[nxt], kbuf[nxt], vbuf[nxt],
      bonds, coords,
      We  + (size_t)l*3*INNER,
      Wo  + (size_t)l*INNER*DIM, bo + (size_t)l*DIM, Wg1 + (size_t)l*3*DIM,
      ln2_g + (size_t)l*DIM, ln2_b + (size_t)l*DIM,
      W1  + (size_t)l*DIM*4*DIM, b1 + (size_t)l*4*DIM,
      W2  + (size_t)l*4*DIM*DIM, b2 + (size_t)l*DIM, Wg2 + (size_t)l*3*DIM,
      ln1_g + (size_t)ln*DIM, ln1_b + (size_t)ln*DIM,
      Wq  + (size_t)ln*DIM*INNER, bq + (size_t)ln*INNER,
      Wkv + (size_t)ln*DIM*2*INNER, bkv + (size_t)ln*2*INNER,
      be  + (size_t)ln*INNER,
      out_w, out_b, (float*)d_out, has_next);
  }
}